// Round 3
// baseline (240.379 us; speedup 1.0000x reference)
//
#include <hip/hip_runtime.h>
#include <math.h>

#define BB 4
#define CC 256
#define NN 4096
#define KV 64

using half8 = __attribute__((ext_vector_type(8))) _Float16;
using f32x4 = __attribute__((ext_vector_type(4))) float;
using f32x16 = __attribute__((ext_vector_type(16))) float;

__device__ __forceinline__ unsigned short f2h(float f) {
  _Float16 h = (_Float16)f;   // RNE
  return __builtin_bit_cast(unsigned short, h);
}
__device__ __forceinline__ float h2f(unsigned short u) {
  return (float)__builtin_bit_cast(_Float16, u);
}

// async global->LDS DMA, 16B per lane; LDS dest = wave-uniform base + lane*16
#define ASYNC16(g, l)                                                        \
  __builtin_amdgcn_global_load_lds(                                          \
      (const __attribute__((address_space(1))) unsigned int*)(g),            \
      (__attribute__((address_space(3))) unsigned int*)(l), 16, 0, 0)

// rows of 128B (64 fp16) — used by k_proj only
__device__ __forceinline__ int vt_off(int r, int chunk) {
  return r * 64 + (((chunk ^ r) & 7) << 3);
}

// ---------------- W pre-cast + pre-tile (unchanged) ----------------
__global__ __launch_bounds__(256) void k_wcast(const float* __restrict__ Wq,
    const float* __restrict__ Wk, const float* __restrict__ Wv,
    unsigned short* __restrict__ Wt) {
  int id = blockIdx.x * 256 + threadIdx.x;     // 24576 chunks
  int pos8 = id & 7, o = (id >> 3) & 255, ks = (id >> 11) & 3, p3 = id >> 13;
  const float* W = p3 == 0 ? Wq : (p3 == 1 ? Wk : Wv);
  int c = ks * 64 + ((pos8 ^ o) & 7) * 8;
  const float* src = W + (size_t)o * CC + c;
  float4 a = *(const float4*)(src);
  float4 b4 = *(const float4*)(src + 4);
  union { unsigned short u[8]; uint4 v4; } pk;
  pk.u[0] = f2h(a.x);  pk.u[1] = f2h(a.y);  pk.u[2] = f2h(a.z);  pk.u[3] = f2h(a.w);
  pk.u[4] = f2h(b4.x); pk.u[5] = f2h(b4.y); pk.u[6] = f2h(b4.z); pk.u[7] = f2h(b4.w);
  *(uint4*)(Wt + (size_t)id * 8) = pk.v4;
}

// ---------------- fused 3-projection kernel (unchanged, verified) ----------
__global__ __launch_bounds__(512) void k_proj(const float* __restrict__ x,
    const unsigned short* __restrict__ Wt,
    const float* __restrict__ bq, const float* __restrict__ bk,
    const float* __restrict__ bv,
    unsigned short* __restrict__ Q, unsigned short* __restrict__ K,
    unsigned short* __restrict__ V) {
  __shared__ __align__(16) char ps[110848];
  float* xf = (float*)ps;                               // 64 c x 33 f32 (8448 B)
  unsigned short* xa = (unsigned short*)(ps + 8448);    // 32 n x 64 c fp16 (4096 B)
  unsigned short* wh = (unsigned short*)(ps + 12544);   // 3 x 256 o x 64 c fp16 (98304 B)
  int b = blockIdx.y, n0 = blockIdx.x * 32;
  int t = threadIdx.x, w = t >> 6, lane = t & 63, l15 = lane & 15, quad = lane >> 4;

  f32x4 z = {0.f, 0.f, 0.f, 0.f};
  f32x4 acc[3][2][2];   // [proj][ct: 16-o][mt: 16-n]
#pragma unroll
  for (int p3 = 0; p3 < 3; ++p3)
#pragma unroll
    for (int ct = 0; ct < 2; ++ct)
#pragma unroll
      for (int mt = 0; mt < 2; ++mt) acc[p3][ct][mt] = z;

  for (int ks = 0; ks < 4; ++ks) {
    if (ks) __syncthreads();   // all waves done with xa/wh of prev ks
    // W DMA: 3 projs x 32 KB, linear copy of pre-tiled Wt
#pragma unroll
    for (int p3 = 0; p3 < 3; ++p3) {
      const char* wb = (const char*)(Wt + (size_t)(p3 * 4 + ks) * 16384);
#pragma unroll
      for (int p = 0; p < 4; ++p) {
        int c = p * 512 + t;
        ASYNC16(wb + c * 16, &wh[p3 * 16384 + (p * 512 + (w << 6)) * 8]);
      }
    }
    // x f32 tile: 64 c-rows x 32 n, coalesced 16B loads
    {
      int c = t >> 3, nl = (t & 7) * 4;
      float4 v = *(const float4*)(x + ((size_t)b * CC + ks * 64 + c) * NN + n0 + nl);
      float* d = xf + c * 33 + nl;
      d[0] = v.x; d[1] = v.y; d[2] = v.z; d[3] = v.w;
    }
    __syncthreads();   // xf visible; W DMA drained
    // transpose-pack: xa[n][c] fp16 (A-layout, swizzled), once per ks
    {
      int n = t >> 4, cb = (t & 15) * 4;
      union { unsigned short u[4]; ushort4 v4; } tmp;
#pragma unroll
      for (int i = 0; i < 4; ++i) tmp.u[i] = f2h(xf[(cb + i) * 33 + n]);
      int ch = cb >> 3;
      *(ushort4*)&xa[n * 64 + (((ch ^ n) & 7) << 3) + (cb & 7)] = tmp.v4;
    }
    __syncthreads();   // xa visible
#pragma unroll
    for (int kc = 0; kc < 2; ++kc) {
      half8 af[2];
#pragma unroll
      for (int mt = 0; mt < 2; ++mt)
        af[mt] = *(const half8*)&xa[vt_off(mt * 16 + l15, kc * 4 + quad)];
#pragma unroll
      for (int p3 = 0; p3 < 3; ++p3)
#pragma unroll
        for (int ct = 0; ct < 2; ++ct) {
          half8 bf = *(const half8*)&wh[p3 * 16384 + vt_off(w * 32 + ct * 16 + l15, kc * 4 + quad)];
#pragma unroll
          for (int mt = 0; mt < 2; ++mt)
            acc[p3][ct][mt] = __builtin_amdgcn_mfma_f32_16x16x32_f16(af[mt], bf, acc[p3][ct][mt], 0, 0, 0);
        }
    }
  }
  // bias
#pragma unroll
  for (int p3 = 0; p3 < 3; ++p3) {
    const float* bias = p3 == 0 ? bq : (p3 == 1 ? bk : bv);
#pragma unroll
    for (int ct = 0; ct < 2; ++ct) {
      float bv_ = bias[w * 32 + ct * 16 + l15];
#pragma unroll
      for (int mt = 0; mt < 2; ++mt)
#pragma unroll
        for (int r = 0; r < 4; ++r) acc[p3][ct][mt][r] += bv_;
    }
  }
  // epilogues: Q, K via qo[32][264]; V via vo[256][36]
#pragma unroll
  for (int p3 = 0; p3 < 2; ++p3) {
    __syncthreads();
    unsigned short* qo = (unsigned short*)ps;   // 32 x 264
#pragma unroll
    for (int ct = 0; ct < 2; ++ct)
#pragma unroll
      for (int mt = 0; mt < 2; ++mt)
#pragma unroll
        for (int r = 0; r < 4; ++r)
          qo[(mt * 16 + quad * 4 + r) * 264 + w * 32 + ct * 16 + l15] = f2h(acc[p3][ct][mt][r]);
    __syncthreads();
    unsigned short* outp = (p3 == 0 ? Q : K) + ((size_t)b * NN + n0) * CC;
#pragma unroll
    for (int p = 0; p < 2; ++p) {
      int f = p * 8192 + t * 16;
      int n = f >> 9, off = f & 511;
      *(uint4*)((char*)outp + (size_t)n * 512 + off) =
        *(const uint4*)((const char*)&qo[n * 264] + off);
    }
  }
  {
    __syncthreads();
    unsigned short* vo = (unsigned short*)ps;   // 256 x 36
#pragma unroll
    for (int ct = 0; ct < 2; ++ct)
#pragma unroll
      for (int mt = 0; mt < 2; ++mt)
#pragma unroll
        for (int r = 0; r < 4; ++r)
          vo[(w * 32 + ct * 16 + l15) * 36 + mt * 16 + quad * 4 + r] = f2h(acc[2][ct][mt][r]);
    __syncthreads();
#pragma unroll
    for (int p = 0; p < 2; ++p) {
      int id = p * 512 + t;
      int o = id >> 2, off = (id & 3) * 16;
      *(uint4*)((char*)(V + ((size_t)b * CC + o) * NN + n0) + off) =
        *(const uint4*)((const char*)&vo[o * 36] + off);
    }
  }
}

// ---------------- flash attention: 32x32 swapped-operand, reg-resident P ----
// 8 waves = 4 q-groups x 2 k-halves. S^T = mfma(K, Q) (32x32x16): softmax is
// lane-local (col=lane&31=q). P packed+exchanged in-register (shfl_xor 32)
// into PV B-frags; PV = mfma(V, P^T) -> per-k-half partial O' (128 VGPR),
// pair partials summed in epilogue. One counted-vmcnt barrier per body.
__global__ __launch_bounds__(512, 2) void k_flash(const unsigned short* __restrict__ Q,
    const unsigned short* __restrict__ K, const unsigned short* __restrict__ V,
    float* __restrict__ out, unsigned short* __restrict__ opart,
    float* __restrict__ ml, int n_splits) {
  __shared__ __align__(16) char sm[134144];
  unsigned short* kt0 = (unsigned short*)sm;             // 32KB: 64 k x 256 c (xor-5 swz)
  unsigned short* kt1 = (unsigned short*)(sm + 32768);
  unsigned short* vt0 = (unsigned short*)(sm + 65536);   // 32KB: 256 c x 64 k (xor-3 swz)
  unsigned short* vt1 = (unsigned short*)(sm + 98304);
  float* mx  = (float*)(sm + 131072);                    // [par][kth][128] partial max
  float* ll_ = (float*)(sm + 133120);                    // [kth][128] partial lse

  int b = blockIdx.y, q0 = blockIdx.x * 128, split = blockIdx.z;
  int nt = (NN / KV) / n_splits;
  int t = threadIdx.x, w = t >> 6, lane = t & 63;
  int qn = lane & 31, hi = lane >> 5;
  int qg = w >> 1, kth = w & 1;

  // Q B-frags in regs: col=lane&31=q, row c = hi*8+j per 16-c step
  half8 qf[16];
  {
    const unsigned short* qrow = Q + ((size_t)b * NN + q0 + qg * 32 + qn) * CC;
#pragma unroll
    for (int cs = 0; cs < 16; ++cs)
      qf[cs] = *(const half8*)(qrow + cs * 16 + hi * 8);
  }

  f32x16 o_acc[8];   // O'[256c x 32q] partial (own k-half)
#pragma unroll
  for (int ct = 0; ct < 8; ++ct)
#pragma unroll
    for (int r = 0; r < 16; ++r) o_acc[ct][r] = 0.f;

  f32x16 sa;         // S^T tile, carried across body barrier
  float m_i = -INFINITY, lp = 0.f, pm_carry = -INFINITY;

  int it_beg = split * nt, it_end = it_beg + nt;

  auto dma_k = [&](int it, unsigned short* dst) {
    const char* kb = (const char*)(K + ((size_t)b * NN + it * KV) * CC);
#pragma unroll
    for (int p = 0; p < 4; ++p) {
      int c = p * 512 + t;          // chunk 0..2047
      int r = c >> 5, chp = c & 31;
      ASYNC16(kb + r * 512 + ((chp ^ (r & 31)) << 4), &dst[(p * 512 + (w << 6)) * 8]);
    }
  };
  auto dma_v = [&](int it, unsigned short* dst) {
    const char* vb = (const char*)(V + (size_t)b * CC * NN) + it * 128;
#pragma unroll
    for (int p = 0; p < 4; ++p) {
      int c = p * 512 + t;          // chunk 0..2047
      int r = c >> 3, chp = c & 7;
      ASYNC16(vb + (size_t)r * 8192 + ((chp ^ (r & 7)) << 4), &dst[(p * 512 + (w << 6)) * 8]);
    }
  };

  auto qkt = [&](const unsigned short* kc) {
#pragma unroll
    for (int r = 0; r < 16; ++r) sa[r] = 0.f;
    __builtin_amdgcn_s_setprio(1);
#pragma unroll
    for (int cs = 0; cs < 16; ++cs) {
      half8 kf = *(const half8*)&kc[(kth * 32 + qn) * 256 + ((((cs * 2 + hi) ^ qn) & 31) << 3)];
      sa = __builtin_amdgcn_mfma_f32_32x32x16_f16(kf, qf[cs], sa, 0, 0, 0);
    }
    __builtin_amdgcn_s_setprio(0);
  };

  auto partial_max = [&](int par) {
    float pm = sa[0];
#pragma unroll
    for (int r = 1; r < 16; ++r) pm = fmaxf(pm, sa[r]);
    pm = fmaxf(pm, __shfl_xor(pm, 32, 64));
    pm_carry = pm;
    if (lane < 32) mx[(par * 2 + kth) * 128 + qg * 32 + lane] = pm;
  };

  unsigned int g0x, g0y, g1x, g1y, g2x, g2y, g3x, g3y;

  auto finish_sm = [&](int prevpar) {
    float prt = mx[(prevpar * 2 + (kth ^ 1)) * 128 + qg * 32 + qn];
    float mtile = fmaxf(pm_carry, prt);
    float mnew = fmaxf(m_i, mtile);
    float alpha = __expf(m_i - mnew);
    m_i = mnew;
    float ls = 0.f;
#pragma unroll
    for (int r = 0; r < 16; ++r) {
      float p = __expf(sa[r] - mnew);
      sa[r] = p;
      ls += p;
    }
    ls += __shfl_xor(ls, 32, 64);
    lp = lp * alpha + ls;
    g0x = (unsigned)f2h(sa[0])  | ((unsigned)f2h(sa[1])  << 16);
    g0y = (unsigned)f2h(sa[2])  | ((unsigned)f2h(sa[3])  << 16);
    g1x = (unsigned)f2h(sa[4])  | ((unsigned)f2h(sa[5])  << 16);
    g1y = (unsigned)f2h(sa[6])  | ((unsigned)f2h(sa[7])  << 16);
    g2x = (unsigned)f2h(sa[8])  | ((unsigned)f2h(sa[9])  << 16);
    g2y = (unsigned)f2h(sa[10]) | ((unsigned)f2h(sa[11]) << 16);
    g3x = (unsigned)f2h(sa[12]) | ((unsigned)f2h(sa[13]) << 16);
    g3y = (unsigned)f2h(sa[14]) | ((unsigned)f2h(sa[15]) << 16);
    if (!__all(alpha == 1.0f)) {
#pragma unroll
      for (int ct = 0; ct < 8; ++ct)
#pragma unroll
        for (int r = 0; r < 16; ++r) o_acc[ct][r] *= alpha;
    }
  };

  auto pv = [&](const unsigned short* vp) {
    __builtin_amdgcn_s_setprio(1);
#pragma unroll
    for (int s = 0; s < 2; ++s) {
      unsigned int ax = s ? g2x : g0x, ay = s ? g2y : g0y;
      unsigned int bx = s ? g3x : g1x, by = s ? g3y : g1y;
      unsigned int vx = hi ? ax : bx, vy = hi ? ay : by;   // value to send
      unsigned int xx = (unsigned int)__shfl_xor((int)vx, 32, 64);
      unsigned int xy = (unsigned int)__shfl_xor((int)vy, 32, 64);
      union { unsigned int u[4]; half8 h; } bf;
      bf.u[0] = hi ? xx : ax;
      bf.u[1] = hi ? xy : ay;
      bf.u[2] = hi ? bx : xx;
      bf.u[3] = hi ? by : xy;
#pragma unroll
      for (int ct = 0; ct < 8; ++ct) {
        half8 af = *(const half8*)&vp[(ct * 32 + qn) * 64 + ((((kth * 4 + s * 2 + hi) ^ (qn & 7)) & 7) << 3)];
        o_acc[ct] = __builtin_amdgcn_mfma_f32_32x32x16_f16(af, bf.h, o_acc[ct], 0, 0, 0);
      }
    }
    __builtin_amdgcn_s_setprio(0);
  };

  // ---- prologue ----
  dma_k(it_beg, (it_beg & 1) ? kt1 : kt0);
  dma_v(it_beg, (it_beg & 1) ? vt1 : vt0);
  asm volatile("s_waitcnt vmcnt(4) lgkmcnt(0)" ::: "memory");
  __builtin_amdgcn_s_barrier();
  __builtin_amdgcn_sched_barrier(0);
  // first body: QK^T only
  {
    int par = it_beg & 1;
    if (it_beg + 1 < it_end) {
      dma_k(it_beg + 1, par ? kt0 : kt1);
      dma_v(it_beg + 1, par ? vt0 : vt1);
    }
    qkt(par ? kt1 : kt0);
    partial_max(par);
  }
  // ---- main loop ----
  for (int it = it_beg + 1; it < it_end; ++it) {
    int par = it & 1;
    const unsigned short* kcur = par ? kt1 : kt0;
    unsigned short* knxt = par ? kt0 : kt1;
    unsigned short* vprv = par ? vt0 : vt1;
    asm volatile("s_waitcnt vmcnt(4) lgkmcnt(0)" ::: "memory");
    __builtin_amdgcn_s_barrier();
    __builtin_amdgcn_sched_barrier(0);
    if (it + 1 < it_end) dma_k(it + 1, knxt);
    finish_sm(par ^ 1);
    pv(vprv);
    // all waves done reading vprv before its DMA reuse
    __builtin_amdgcn_sched_barrier(0);
    __builtin_amdgcn_s_barrier();
    __builtin_amdgcn_sched_barrier(0);
    if (it + 1 < it_end) dma_v(it + 1, vprv);
    qkt(kcur);
    partial_max(par);
  }
  // ---- tail: finish last tile ----
  __syncthreads();
  {
    int par = (it_end - 1) & 1;
    finish_sm(par);
    pv(par ? vt1 : vt0);
  }

  // ---- lse exchange ----
  if (lane < 32) ll_[kth * 128 + qg * 32 + lane] = lp;
  __syncthreads();
  float* od0 = (float*)sm;                 // 32 x 132
  float* od1 = od0 + 32 * 132;
  float* linv = (float*)(sm + 33792);      // 128 f32
  if (t < 128) {
    float l = ll_[t] + ll_[128 + t];
    linv[t] = (n_splits == 1) ? 1.0f / l : 1.0f;
  }
  if (n_splits != 1 && kth == 0 && lane < 32) {
    size_t qi = (size_t)q0 + qg * 32 + lane;
    float lt = ll_[qg * 32 + lane] + ll_[128 + qg * 32 + lane];
    ml[((size_t)(split * 2 + 0) * BB + b) * NN + qi] = m_i;
    ml[((size_t)(split * 2 + 1) * BB + b) * NN + qi] = lt;
  }
  __syncthreads();

  // ---- epilogue: 8 phases over c, pair partials summed via LDS ----
  float* obf = out + (size_t)b * CC * NN + q0;
  unsigned short* obh = opart + ((size_t)split * BB + b) * CC * NN + q0;
#pragma unroll
  for (int ct = 0; ct < 8; ++ct) {
    float* od = kth ? od1 : od0;
#pragma unroll
    for (int r = 0; r < 16; ++r) {
      int cl = (r & 3) + 8 * (r >> 2) + 4 * hi;
      od[cl * 132 + qg * 32 + qn] = o_acc[ct][r];
    }
    __syncthreads();
    {
      int row = t >> 4, q8 = (t & 15) * 8;
      f32x4 a0 = *(const f32x4*)&od0[row * 132 + q8];
      f32x4 a1 = *(const f32x4*)&od0[row * 132 + q8 + 4];
      f32x4 b0 = *(const f32x4*)&od1[row * 132 + q8];
      f32x4 b1 = *(const f32x4*)&od1[row * 132 + q8 + 4];
      f32x4 l0 = *(const f32x4*)&linv[q8];
      f32x4 l1 = *(const f32x4*)&linv[q8 + 4];
      f32x4 s0, s1;
#pragma unroll
      for (int i = 0; i < 4; ++i) {
        s0[i] = (a0[i] + b0[i]) * l0[i];
        s1[i] = (a1[i] + b1[i]) * l1[i];
      }
      if (n_splits == 1) {
        *(f32x4*)(obf + (size_t)(ct * 32 + row) * NN + q8) = s0;
        *(f32x4*)(obf + (size_t)(ct * 32 + row) * NN + q8 + 4) = s1;
      } else {
        union { unsigned short u[8]; uint4 v4; } tmp;
#pragma unroll
        for (int i = 0; i < 4; ++i) { tmp.u[i] = f2h(s0[i]); tmp.u[4 + i] = f2h(s1[i]); }
        *(uint4*)(obh + (size_t)(ct * 32 + row) * NN + q8) = tmp.v4;
      }
    }
    __syncthreads();
  }
}

// ---------------- merge of 2 key-splits ----------------
__global__ __launch_bounds__(256) void k_merge(const unsigned short* __restrict__ opart,
    const float* __restrict__ ml, float* __restrict__ out) {
  size_t i = ((size_t)blockIdx.x * 256 + threadIdx.x) * 4;
  int n = (int)(i & (NN - 1));
  int b = (int)(i >> 20);   // i / (CC*NN)
  float4 m1 = *(const float4*)(ml + ((size_t)(0 * BB) + b) * NN + n);
  float4 l1 = *(const float4*)(ml + ((size_t)(1 * BB) + b) * NN + n);
  float4 m2 = *(const float4*)(ml + ((size_t)(2 * BB) + b) * NN + n);
  float4 l2 = *(const float4*)(ml + ((size_t)(3 * BB) + b) * NN + n);
  ushort4 o1 = *(const ushort4*)(opart + i);
  ushort4 o2 = *(const ushort4*)(opart + (size_t)BB * CC * NN + i);
  float4 res;
#define MRG(f, comp) { \
    float M = fmaxf(m1.f, m2.f); \
    float e1 = __expf(m1.f - M), e2 = __expf(m2.f - M); \
    res.f = (e1 * h2f(o1.comp) + e2 * h2f(o2.comp)) / (e1 * l1.f + e2 * l2.f); }
  MRG(x, x) MRG(y, y) MRG(z, z) MRG(w, w)
#undef MRG
  *(float4*)(out + i) = res;
}

extern "C" void kernel_launch(void* const* d_in, const int* in_sizes, int n_in,
                              void* d_out, int out_size, void* d_ws, size_t ws_size,
                              hipStream_t stream) {
  const float* x  = (const float*)d_in[0];
  const float* Wq = (const float*)d_in[1];
  const float* bq = (const float*)d_in[2];
  const float* Wk = (const float*)d_in[3];
  const float* bk = (const float*)d_in[4];
  const float* Wv = (const float*)d_in[5];
  const float* bv = (const float*)d_in[6];
  float* out = (float*)d_out;
  char* ws = (char*)d_ws;
  const size_t MB = 1024 * 1024;
  unsigned short* Qb = (unsigned short*)(ws);             // 8 MB fp16 (B,N,C)
  unsigned short* Kb = (unsigned short*)(ws + 8 * MB);    // 8 MB fp16 (B,N,C)
  unsigned short* Vb = (unsigned short*)(ws + 16 * MB);   // 8 MB fp16 (B,C,N)
  unsigned short* Op = (unsigned short*)(ws + 24 * MB);   // 16 MB fp16 partials
  float*          Ml = (float*)(ws + 40 * MB);            // 256 KB

  int ns = (ws_size >= 41 * MB) ? 2 : 1;
  unsigned short* Wt = (unsigned short*)(ns == 2 ? ws + 40 * MB + 256 * 1024
                                                 : ws + 24 * MB);

  k_wcast<<<dim3(96), 256, 0, stream>>>(Wq, Wk, Wv, Wt);
  k_proj<<<dim3(128, 4), 512, 0, stream>>>(x, Wt, bq, bk, bv, Qb, Kb, Vb);

  k_flash<<<dim3(32, 4, ns), 512, 0, stream>>>(Qb, Kb, Vb, out, Op, Ml, ns);
  if (ns == 2) k_merge<<<dim3(4096), 256, 0, stream>>>(Op, Ml, out);
}

// Round 4
// 213.070 us; speedup vs baseline: 1.1282x; 1.1282x over previous
//
#include <hip/hip_runtime.h>
#include <math.h>

#define BB 4
#define CC 256
#define NN 4096
#define KV 64

using half8 = __attribute__((ext_vector_type(8))) _Float16;
using f32x4 = __attribute__((ext_vector_type(4))) float;
using f32x16 = __attribute__((ext_vector_type(16))) float;

__device__ __forceinline__ unsigned short f2h(float f) {
  _Float16 h = (_Float16)f;   // RNE
  return __builtin_bit_cast(unsigned short, h);
}
__device__ __forceinline__ float h2f(unsigned short u) {
  return (float)__builtin_bit_cast(_Float16, u);
}

// async global->LDS DMA, 16B per lane; LDS dest = wave-uniform base + lane*16
#define ASYNC16(g, l)                                                        \
  __builtin_amdgcn_global_load_lds(                                          \
      (const __attribute__((address_space(1))) unsigned int*)(g),            \
      (__attribute__((address_space(3))) unsigned int*)(l), 16, 0, 0)

// rows of 128B (64 fp16) — used by k_proj only
__device__ __forceinline__ int vt_off(int r, int chunk) {
  return r * 64 + (((chunk ^ r) & 7) << 3);
}

// ---------------- W pre-cast + pre-tile (unchanged) ----------------
__global__ __launch_bounds__(256) void k_wcast(const float* __restrict__ Wq,
    const float* __restrict__ Wk, const float* __restrict__ Wv,
    unsigned short* __restrict__ Wt) {
  int id = blockIdx.x * 256 + threadIdx.x;     // 24576 chunks
  int pos8 = id & 7, o = (id >> 3) & 255, ks = (id >> 11) & 3, p3 = id >> 13;
  const float* W = p3 == 0 ? Wq : (p3 == 1 ? Wk : Wv);
  int c = ks * 64 + ((pos8 ^ o) & 7) * 8;
  const float* src = W + (size_t)o * CC + c;
  float4 a = *(const float4*)(src);
  float4 b4 = *(const float4*)(src + 4);
  union { unsigned short u[8]; uint4 v4; } pk;
  pk.u[0] = f2h(a.x);  pk.u[1] = f2h(a.y);  pk.u[2] = f2h(a.z);  pk.u[3] = f2h(a.w);
  pk.u[4] = f2h(b4.x); pk.u[5] = f2h(b4.y); pk.u[6] = f2h(b4.z); pk.u[7] = f2h(b4.w);
  *(uint4*)(Wt + (size_t)id * 8) = pk.v4;
}

// ---------------- fused 3-projection kernel (unchanged, verified) ----------
__global__ __launch_bounds__(512) void k_proj(const float* __restrict__ x,
    const unsigned short* __restrict__ Wt,
    const float* __restrict__ bq, const float* __restrict__ bk,
    const float* __restrict__ bv,
    unsigned short* __restrict__ Q, unsigned short* __restrict__ K,
    unsigned short* __restrict__ V) {
  __shared__ __align__(16) char ps[110848];
  float* xf = (float*)ps;                               // 64 c x 33 f32 (8448 B)
  unsigned short* xa = (unsigned short*)(ps + 8448);    // 32 n x 64 c fp16 (4096 B)
  unsigned short* wh = (unsigned short*)(ps + 12544);   // 3 x 256 o x 64 c fp16 (98304 B)
  int b = blockIdx.y, n0 = blockIdx.x * 32;
  int t = threadIdx.x, w = t >> 6, lane = t & 63, l15 = lane & 15, quad = lane >> 4;

  f32x4 z = {0.f, 0.f, 0.f, 0.f};
  f32x4 acc[3][2][2];   // [proj][ct: 16-o][mt: 16-n]
#pragma unroll
  for (int p3 = 0; p3 < 3; ++p3)
#pragma unroll
    for (int ct = 0; ct < 2; ++ct)
#pragma unroll
      for (int mt = 0; mt < 2; ++mt) acc[p3][ct][mt] = z;

  for (int ks = 0; ks < 4; ++ks) {
    if (ks) __syncthreads();   // all waves done with xa/wh of prev ks
    // W DMA: 3 projs x 32 KB, linear copy of pre-tiled Wt
#pragma unroll
    for (int p3 = 0; p3 < 3; ++p3) {
      const char* wb = (const char*)(Wt + (size_t)(p3 * 4 + ks) * 16384);
#pragma unroll
      for (int p = 0; p < 4; ++p) {
        int c = p * 512 + t;
        ASYNC16(wb + c * 16, &wh[p3 * 16384 + (p * 512 + (w << 6)) * 8]);
      }
    }
    // x f32 tile: 64 c-rows x 32 n, coalesced 16B loads
    {
      int c = t >> 3, nl = (t & 7) * 4;
      float4 v = *(const float4*)(x + ((size_t)b * CC + ks * 64 + c) * NN + n0 + nl);
      float* d = xf + c * 33 + nl;
      d[0] = v.x; d[1] = v.y; d[2] = v.z; d[3] = v.w;
    }
    __syncthreads();   // xf visible; W DMA drained
    // transpose-pack: xa[n][c] fp16 (A-layout, swizzled), once per ks
    {
      int n = t >> 4, cb = (t & 15) * 4;
      union { unsigned short u[4]; ushort4 v4; } tmp;
#pragma unroll
      for (int i = 0; i < 4; ++i) tmp.u[i] = f2h(xf[(cb + i) * 33 + n]);
      int ch = cb >> 3;
      *(ushort4*)&xa[n * 64 + (((ch ^ n) & 7) << 3) + (cb & 7)] = tmp.v4;
    }
    __syncthreads();   // xa visible
#pragma unroll
    for (int kc = 0; kc < 2; ++kc) {
      half8 af[2];
#pragma unroll
      for (int mt = 0; mt < 2; ++mt)
        af[mt] = *(const half8*)&xa[vt_off(mt * 16 + l15, kc * 4 + quad)];
#pragma unroll
      for (int p3 = 0; p3 < 3; ++p3)
#pragma unroll
        for (int ct = 0; ct < 2; ++ct) {
          half8 bf = *(const half8*)&wh[p3 * 16384 + vt_off(w * 32 + ct * 16 + l15, kc * 4 + quad)];
#pragma unroll
          for (int mt = 0; mt < 2; ++mt)
            acc[p3][ct][mt] = __builtin_amdgcn_mfma_f32_16x16x32_f16(af[mt], bf, acc[p3][ct][mt], 0, 0, 0);
        }
    }
  }
  // bias
#pragma unroll
  for (int p3 = 0; p3 < 3; ++p3) {
    const float* bias = p3 == 0 ? bq : (p3 == 1 ? bk : bv);
#pragma unroll
    for (int ct = 0; ct < 2; ++ct) {
      float bv_ = bias[w * 32 + ct * 16 + l15];
#pragma unroll
      for (int mt = 0; mt < 2; ++mt)
#pragma unroll
        for (int r = 0; r < 4; ++r) acc[p3][ct][mt][r] += bv_;
    }
  }
  // epilogues: Q, K via qo[32][264]; V via vo[256][36]
#pragma unroll
  for (int p3 = 0; p3 < 2; ++p3) {
    __syncthreads();
    unsigned short* qo = (unsigned short*)ps;   // 32 x 264
#pragma unroll
    for (int ct = 0; ct < 2; ++ct)
#pragma unroll
      for (int mt = 0; mt < 2; ++mt)
#pragma unroll
        for (int r = 0; r < 4; ++r)
          qo[(mt * 16 + quad * 4 + r) * 264 + w * 32 + ct * 16 + l15] = f2h(acc[p3][ct][mt][r]);
    __syncthreads();
    unsigned short* outp = (p3 == 0 ? Q : K) + ((size_t)b * NN + n0) * CC;
#pragma unroll
    for (int p = 0; p < 2; ++p) {
      int f = p * 8192 + t * 16;
      int n = f >> 9, off = f & 511;
      *(uint4*)((char*)outp + (size_t)n * 512 + off) =
        *(const uint4*)((const char*)&qo[n * 264] + off);
    }
  }
  {
    __syncthreads();
    unsigned short* vo = (unsigned short*)ps;   // 256 x 36
#pragma unroll
    for (int ct = 0; ct < 2; ++ct)
#pragma unroll
      for (int mt = 0; mt < 2; ++mt)
#pragma unroll
        for (int r = 0; r < 4; ++r)
          vo[(w * 32 + ct * 16 + l15) * 36 + mt * 16 + quad * 4 + r] = f2h(acc[2][ct][mt][r]);
    __syncthreads();
#pragma unroll
    for (int p = 0; p < 2; ++p) {
      int id = p * 512 + t;
      int o = id >> 2, off = (id & 3) * 16;
      *(uint4*)((char*)(V + ((size_t)b * CC + o) * NN + n0) + off) =
        *(const uint4*)((const char*)&vo[o * 36] + off);
    }
  }
}

// ---------------- flash attention: sticky-max, 1 barrier/body ----------------
// 8 waves = 4 q-groups x 2 k-halves, 32x32 swapped-operand (layouts verified
// in R3). Sticky threshold-max (THR=8): per-wave (m,l,O') with NO per-body
// cross-wave exchange; halves combined in epilogue via exp(m_h-M) weights.
// Body: __syncthreads -> DMA(it+1) -> QK^T(it) -> exp/pack -> PV(it).
__global__ __launch_bounds__(512, 2) void k_flash(const unsigned short* __restrict__ Q,
    const unsigned short* __restrict__ K, const unsigned short* __restrict__ V,
    float* __restrict__ out, unsigned short* __restrict__ opart,
    float* __restrict__ ml, int n_splits) {
  __shared__ __align__(16) char sm[133120];
  unsigned short* kt0 = (unsigned short*)sm;             // 32KB: 64 k x 256 c (xor swz)
  unsigned short* kt1 = (unsigned short*)(sm + 32768);
  unsigned short* vt0 = (unsigned short*)(sm + 65536);   // 32KB: 256 c x 64 k (xor swz)
  unsigned short* vt1 = (unsigned short*)(sm + 98304);
  float* mm_ = (float*)(sm + 131072);                    // [kth][128] partial max
  float* ll_ = (float*)(sm + 132096);                    // [kth][128] partial lse

  int b = blockIdx.y, q0 = blockIdx.x * 128, split = blockIdx.z;
  int nt = (NN / KV) / n_splits;
  int t = threadIdx.x, w = t >> 6, lane = t & 63;
  int qn = lane & 31, hi = lane >> 5;
  int qg = w >> 1, kth = w & 1;

  // Q B-frags in regs: col=lane&31=q, row c = hi*8+j per 16-c step
  half8 qf[16];
  {
    const unsigned short* qrow = Q + ((size_t)b * NN + q0 + qg * 32 + qn) * CC;
#pragma unroll
    for (int cs = 0; cs < 16; ++cs)
      qf[cs] = *(const half8*)(qrow + cs * 16 + hi * 8);
  }

  f32x16 o_acc[8];   // O'[256c x 32q] partial (own k-half)
#pragma unroll
  for (int ct = 0; ct < 8; ++ct)
#pragma unroll
    for (int r = 0; r < 16; ++r) o_acc[ct][r] = 0.f;

  float m_i = -INFINITY, lp = 0.f;

  int it_beg = split * nt, it_end = it_beg + nt;

  auto dma_k = [&](int it, unsigned short* dst) {
    const char* kb = (const char*)(K + ((size_t)b * NN + it * KV) * CC);
#pragma unroll
    for (int p = 0; p < 4; ++p) {
      int c = p * 512 + t;          // chunk 0..2047
      int r = c >> 5, chp = c & 31;
      ASYNC16(kb + r * 512 + ((chp ^ (r & 31)) << 4), &dst[(p * 512 + (w << 6)) * 8]);
    }
  };
  auto dma_v = [&](int it, unsigned short* dst) {
    const char* vb = (const char*)(V + (size_t)b * CC * NN) + it * 128;
#pragma unroll
    for (int p = 0; p < 4; ++p) {
      int c = p * 512 + t;          // chunk 0..2047
      int r = c >> 3, chp = c & 7;
      ASYNC16(vb + (size_t)r * 8192 + ((chp ^ (r & 7)) << 4), &dst[(p * 512 + (w << 6)) * 8]);
    }
  };

  dma_k(it_beg, (it_beg & 1) ? kt1 : kt0);
  dma_v(it_beg, (it_beg & 1) ? vt1 : vt0);

  for (int it = it_beg; it < it_end; ++it) {
    int par = it & 1;
    const unsigned short* kcur = par ? kt1 : kt0;
    const unsigned short* vcur = par ? vt1 : vt0;

    __syncthreads();   // drains K(it)+V(it) DMA; protects prev-par buffers

    if (it + 1 < it_end) {
      dma_k(it + 1, par ? kt0 : kt1);
      dma_v(it + 1, par ? vt0 : vt1);
    }

    // ---- QK^T(it): S^T = mfma(K, Q), lane col = q ----
    f32x16 sa;
#pragma unroll
    for (int r = 0; r < 16; ++r) sa[r] = 0.f;
    __builtin_amdgcn_s_setprio(1);
#pragma unroll
    for (int cs = 0; cs < 16; ++cs) {
      half8 kf = *(const half8*)&kcur[(kth * 32 + qn) * 256 + ((((cs * 2 + hi) ^ qn) & 31) << 3)];
      sa = __builtin_amdgcn_mfma_f32_32x32x16_f16(kf, qf[cs], sa, 0, 0, 0);
    }
    __builtin_amdgcn_s_setprio(0);

    // ---- sticky-max softmax (common path: no rescale, no exchange) ----
    float pm = sa[0];
#pragma unroll
    for (int r = 1; r < 16; ++r) pm = fmaxf(pm, sa[r]);
    pm = fmaxf(pm, __shfl_xor(pm, 32, 64));
    if (!__all(pm <= m_i + 8.0f)) {
      float mnew = fmaxf(m_i, pm);
      float alpha = __expf(m_i - mnew);   // 0 on first tile (m_i = -inf)
      m_i = mnew;
      lp *= alpha;
#pragma unroll
      for (int ct = 0; ct < 8; ++ct)
#pragma unroll
        for (int r = 0; r < 16; ++r) o_acc[ct][r] *= alpha;
    }
    float ls = 0.f;
#pragma unroll
    for (int r = 0; r < 16; ++r) {
      float p = __expf(sa[r] - m_i);   // <= e^8, fp16-safe
      sa[r] = p;
      ls += p;
    }
    lp += ls;   // lane-partial (own 16 k-rows); hi-pair summed in epilogue

    unsigned int g0x = (unsigned)f2h(sa[0])  | ((unsigned)f2h(sa[1])  << 16);
    unsigned int g0y = (unsigned)f2h(sa[2])  | ((unsigned)f2h(sa[3])  << 16);
    unsigned int g1x = (unsigned)f2h(sa[4])  | ((unsigned)f2h(sa[5])  << 16);
    unsigned int g1y = (unsigned)f2h(sa[6])  | ((unsigned)f2h(sa[7])  << 16);
    unsigned int g2x = (unsigned)f2h(sa[8])  | ((unsigned)f2h(sa[9])  << 16);
    unsigned int g2y = (unsigned)f2h(sa[10]) | ((unsigned)f2h(sa[11]) << 16);
    unsigned int g3x = (unsigned)f2h(sa[12]) | ((unsigned)f2h(sa[13]) << 16);
    unsigned int g3y = (unsigned)f2h(sa[14]) | ((unsigned)f2h(sa[15]) << 16);

    // ---- PV(it): O' += mfma(V, P^T) ----
    __builtin_amdgcn_s_setprio(1);
#pragma unroll
    for (int s = 0; s < 2; ++s) {
      unsigned int ax = s ? g2x : g0x, ay = s ? g2y : g0y;
      unsigned int bx = s ? g3x : g1x, by = s ? g3y : g1y;
      unsigned int vx = hi ? ax : bx, vy = hi ? ay : by;   // value to send
      unsigned int xx = (unsigned int)__shfl_xor((int)vx, 32, 64);
      unsigned int xy = (unsigned int)__shfl_xor((int)vy, 32, 64);
      union { unsigned int u[4]; half8 h; } bf;
      bf.u[0] = hi ? xx : ax;
      bf.u[1] = hi ? xy : ay;
      bf.u[2] = hi ? bx : xx;
      bf.u[3] = hi ? by : xy;
#pragma unroll
      for (int ct = 0; ct < 8; ++ct) {
        half8 af = *(const half8*)&vcur[(ct * 32 + qn) * 64 + ((((kth * 4 + s * 2 + hi) ^ (qn & 7)) & 7) << 3)];
        o_acc[ct] = __builtin_amdgcn_mfma_f32_32x32x16_f16(af, bf.h, o_acc[ct], 0, 0, 0);
      }
    }
    __builtin_amdgcn_s_setprio(0);
  }

  // ---- combine k-halves: weights exp(m_h - M), l = sum of weighted lse ----
  lp += __shfl_xor(lp, 32, 64);   // full row sum for own half
  if (lane < 32) {
    mm_[kth * 128 + qg * 32 + lane] = m_i;
    ll_[kth * 128 + qg * 32 + lane] = lp;
  }
  __syncthreads();
  float m_oth = mm_[(kth ^ 1) * 128 + qg * 32 + qn];
  float l_oth = ll_[(kth ^ 1) * 128 + qg * 32 + qn];
  float M = fmaxf(m_i, m_oth);
  float myw = __expf(m_i - M);
  float lcomb = lp * myw + l_oth * __expf(m_oth - M);

  float* od0 = (float*)sm;                 // 32 x 132 (kt region dead)
  float* od1 = od0 + 32 * 132;
  float* linv = (float*)(sm + 33792);      // 128 f32
  if (kth == 0 && lane < 32) {
    int q = qg * 32 + lane;
    linv[q] = 1.0f / lcomb;
    if (n_splits != 1) {
      size_t qi = (size_t)q0 + q;
      ml[((size_t)(split * 2 + 0) * BB + b) * NN + qi] = M;
      ml[((size_t)(split * 2 + 1) * BB + b) * NN + qi] = lcomb;
    }
  }
  __syncthreads();

  // ---- epilogue: 8 phases over c; per-half scale folded into od write ----
  float* obf = out + (size_t)b * CC * NN + q0;
  unsigned short* obh = opart + ((size_t)split * BB + b) * CC * NN + q0;
#pragma unroll
  for (int ct = 0; ct < 8; ++ct) {
    float* od = kth ? od1 : od0;
#pragma unroll
    for (int r = 0; r < 16; ++r) {
      int cl = (r & 3) + 8 * (r >> 2) + 4 * hi;
      od[cl * 132 + qg * 32 + qn] = o_acc[ct][r] * myw;
    }
    __syncthreads();
    {
      int row = t >> 4, q8 = (t & 15) * 8;
      f32x4 a0 = *(const f32x4*)&od0[row * 132 + q8];
      f32x4 a1 = *(const f32x4*)&od0[row * 132 + q8 + 4];
      f32x4 b0 = *(const f32x4*)&od1[row * 132 + q8];
      f32x4 b1 = *(const f32x4*)&od1[row * 132 + q8 + 4];
      f32x4 l0 = *(const f32x4*)&linv[q8];
      f32x4 l1 = *(const f32x4*)&linv[q8 + 4];
      f32x4 s0, s1;
#pragma unroll
      for (int i = 0; i < 4; ++i) {
        s0[i] = (a0[i] + b0[i]) * l0[i];
        s1[i] = (a1[i] + b1[i]) * l1[i];
      }
      if (n_splits == 1) {
        *(f32x4*)(obf + (size_t)(ct * 32 + row) * NN + q8) = s0;
        *(f32x4*)(obf + (size_t)(ct * 32 + row) * NN + q8 + 4) = s1;
      } else {
        // store per-split NORMALIZED O (O(1), fp16-safe); merge reweights by l
        union { unsigned short u[8]; uint4 v4; } tmp;
#pragma unroll
        for (int i = 0; i < 4; ++i) { tmp.u[i] = f2h(s0[i]); tmp.u[4 + i] = f2h(s1[i]); }
        *(uint4*)(obh + (size_t)(ct * 32 + row) * NN + q8) = tmp.v4;
      }
    }
    __syncthreads();
  }
}

// ---------------- merge of 2 key-splits (normalized partials) ----------------
__global__ __launch_bounds__(256) void k_merge(const unsigned short* __restrict__ opart,
    const float* __restrict__ ml, float* __restrict__ out) {
  size_t i = ((size_t)blockIdx.x * 256 + threadIdx.x) * 4;
  int n = (int)(i & (NN - 1));
  int b = (int)(i >> 20);   // i / (CC*NN)
  float4 m1 = *(const float4*)(ml + ((size_t)(0 * BB) + b) * NN + n);
  float4 l1 = *(const float4*)(ml + ((size_t)(1 * BB) + b) * NN + n);
  float4 m2 = *(const float4*)(ml + ((size_t)(2 * BB) + b) * NN + n);
  float4 l2 = *(const float4*)(ml + ((size_t)(3 * BB) + b) * NN + n);
  ushort4 o1 = *(const ushort4*)(opart + i);
  ushort4 o2 = *(const ushort4*)(opart + (size_t)BB * CC * NN + i);
  float4 res;
#define MRG(f, comp) { \
    float M = fmaxf(m1.f, m2.f); \
    float e1 = __expf(m1.f - M) * l1.f, e2 = __expf(m2.f - M) * l2.f; \
    res.f = (e1 * h2f(o1.comp) + e2 * h2f(o2.comp)) / (e1 + e2); }
  MRG(x, x) MRG(y, y) MRG(z, z) MRG(w, w)
#undef MRG
  *(float4*)(out + i) = res;
}

extern "C" void kernel_launch(void* const* d_in, const int* in_sizes, int n_in,
                              void* d_out, int out_size, void* d_ws, size_t ws_size,
                              hipStream_t stream) {
  const float* x  = (const float*)d_in[0];
  const float* Wq = (const float*)d_in[1];
  const float* bq = (const float*)d_in[2];
  const float* Wk = (const float*)d_in[3];
  const float* bk = (const float*)d_in[4];
  const float* Wv = (const float*)d_in[5];
  const float* bv = (const float*)d_in[6];
  float* out = (float*)d_out;
  char* ws = (char*)d_ws;
  const size_t MB = 1024 * 1024;
  unsigned short* Qb = (unsigned short*)(ws);             // 8 MB fp16 (B,N,C)
  unsigned short* Kb = (unsigned short*)(ws + 8 * MB);    // 8 MB fp16 (B,N,C)
  unsigned short* Vb = (unsigned short*)(ws + 16 * MB);   // 8 MB fp16 (B,C,N)
  unsigned short* Op = (unsigned short*)(ws + 24 * MB);   // 16 MB fp16 partials
  float*          Ml = (float*)(ws + 40 * MB);            // 256 KB

  int ns = (ws_size >= 41 * MB) ? 2 : 1;
  unsigned short* Wt = (unsigned short*)(ns == 2 ? ws + 40 * MB + 256 * 1024
                                                 : ws + 24 * MB);

  k_wcast<<<dim3(96), 256, 0, stream>>>(Wq, Wk, Wv, Wt);
  k_proj<<<dim3(128, 4), 512, 0, stream>>>(x, Wt, bq, bk, bv, Qb, Kb, Vb);

  k_flash<<<dim3(32, 4, ns), 512, 0, stream>>>(Qb, Kb, Vb, out, Op, Ml, ns);
  if (ns == 2) k_merge<<<dim3(4096), 256, 0, stream>>>(Op, Ml, out);
}